// Round 1
// baseline (570.320 us; speedup 1.0000x reference)
//
#include <hip/hip_runtime.h>

// HGNN conv: out = degv ⊙ (H @ ((w*deg_e) ⊙ (H^T @ (degv ⊙ (x@W))))) + bias ; w = sigmoid(H^T (x V))
// N=8192 nodes, E=4096 edges, F=512. fp32 in/out; GEMM chain in bf16 MFMA (2% absmax tolerance),
// sigmoid/deg path in fp32 (sigmoid at |z|~0 needs precision).

#define N_NODES 8192
#define N_EDGES 4096
#define FT 512

typedef short bf16x8 __attribute__((ext_vector_type(8)));
typedef float f32x4 __attribute__((ext_vector_type(4)));
typedef unsigned short u16;
typedef unsigned int u32;

__device__ __forceinline__ u16 f2b(float f) {
    union { float f; u32 u; } v; v.f = f;
    u32 r = v.u + 0x7FFFu + ((v.u >> 16) & 1u);   // RNE
    return (u16)(r >> 16);
}
__device__ __forceinline__ float b2f(u16 h) {
    union { u32 u; float f; } v; v.u = ((u32)h) << 16; return v.f;
}

__device__ __forceinline__ float ldf(const float* p) { return *p; }
__device__ __forceinline__ float ldf(const u16* p) { return b2f(*p); }
__device__ __forceinline__ void stf(float* p, float v) { *p = v; }
__device__ __forceinline__ void stf(u16* p, float v) { *p = f2b(v); }

// ---------------- small kernels ----------------

__global__ __launch_bounds__(256) void zero_kernel(float* p, int n) {
    int i = blockIdx.x * 256 + threadIdx.x;
    if (i < n) p[i] = 0.f;
}

// xv[n] = x[n,:] . V   (one wave per row)
__global__ __launch_bounds__(256) void xv_kernel(const float* __restrict__ x,
                                                 const float* __restrict__ V,
                                                 float* __restrict__ xv) {
    int row = blockIdx.x * 4 + (threadIdx.x >> 6);
    int lane = threadIdx.x & 63;
    const float4* xr = (const float4*)(x + (size_t)row * FT);
    const float4* vr = (const float4*)V;
    float acc = 0.f;
#pragma unroll
    for (int i = 0; i < 2; i++) {
        int idx = i * 64 + lane;
        float4 a = xr[idx], b = vr[idx];
        acc += a.x * b.x + a.y * b.y + a.z * b.z + a.w * b.w;
    }
#pragma unroll
    for (int off = 32; off; off >>= 1) acc += __shfl_down(acc, off);
    if (lane == 0) xv[row] = acc;
}

// zsum[e] += sum_n H[n,e]*xv[n];  desum[e] += sum_n H[n,e]   (row-chunked, atomic combine)
__global__ __launch_bounds__(256) void colsum_kernel(const float* __restrict__ H,
                                                     const float* __restrict__ xv,
                                                     float* __restrict__ zsum,
                                                     float* __restrict__ desum) {
    int e = blockIdx.x * 256 + threadIdx.x;
    int n0 = blockIdx.y * 128;
    float z = 0.f, d = 0.f;
#pragma unroll 4
    for (int i = 0; i < 128; i++) {
        float h = H[(size_t)(n0 + i) * N_EDGES + e];
        z += h * xv[n0 + i];
        d += h;
    }
    atomicAdd(zsum + e, z);
    atomicAdd(desum + e, d);
}

// w[e] = sigmoid(z[e]); wde[e] = w[e]*deg_e[e]
__global__ __launch_bounds__(256) void sigmoid_kernel(const float* __restrict__ zsum,
                                                      const float* __restrict__ desum,
                                                      float* __restrict__ w_out,
                                                      float* __restrict__ wde) {
    int e = blockIdx.x * 256 + threadIdx.x;
    float z = zsum[e];
    float wv = 1.f / (1.f + expf(-z));
    w_out[e] = wv;
    wde[e] = wv * desum[e];
}

// degv[n] = H[n,:] . w   (one wave per row)
__global__ __launch_bounds__(256) void degv_kernel(const float* __restrict__ H,
                                                   const float* __restrict__ w,
                                                   float* __restrict__ degv) {
    int row = blockIdx.x * 4 + (threadIdx.x >> 6);
    int lane = threadIdx.x & 63;
    const float4* hr = (const float4*)(H + (size_t)row * N_EDGES);
    const float4* wr = (const float4*)w;
    float acc = 0.f;
#pragma unroll
    for (int i = 0; i < 16; i++) {
        int idx = i * 64 + lane;
        float4 h = hr[idx], ww = wr[idx];
        acc += h.x * ww.x + h.y * ww.y + h.z * ww.z + h.w * ww.w;
    }
#pragma unroll
    for (int off = 32; off; off >>= 1) acc += __shfl_down(acc, off);
    if (lane == 0) degv[row] = acc;
}

// dst[c,r] = src[r,c]; src (R,C), dst (C,R). 32x32 tiles.
template <typename ST, typename DT>
__global__ void transpose_kernel(const ST* __restrict__ src, DT* __restrict__ dst, int R, int C) {
    __shared__ float tile[32][33];
    int tx = threadIdx.x, ty = threadIdx.y;
    int c = blockIdx.x * 32 + tx;
    int r0 = blockIdx.y * 32;
#pragma unroll
    for (int i = 0; i < 4; i++)
        tile[ty + i * 8][tx] = ldf(&src[(size_t)(r0 + ty + i * 8) * C + c]);
    __syncthreads();
    int r = r0 + tx;
#pragma unroll
    for (int i = 0; i < 4; i++)
        stf(&dst[(size_t)(blockIdx.x * 32 + ty + i * 8) * R + r], tile[tx][ty + i * 8]);
}

// ---------------- MFMA GEMM ----------------
// C[m,n] = rscale[m] * sum_k A[m,k]*B[k,n] (+ bias[n])
// A: fp32. ALAYOUT=0: A[m,k]=A[m*lda+k] (row-major). ALAYOUT=1: A[m,k]=A[k*lda+m] (H^T case).
// Bt: bf16, B-transposed layout: B[k,n] = Bt[n*ldb + k].
// 128x64 tile, BK=32, 4 waves (2x2), each wave 64x32 via 4x2 of 16x16x32 MFMAs.

#define BM 128
#define BN 64
#define BK 32
#define LSTR 40   // LDS row stride in bf16 elts (BK+8 pad): frag reads land 2-way on banks = free

template <int ALAYOUT, typename OT, bool BIAS>
__global__ __launch_bounds__(256)
void gemm_bf16(const float* __restrict__ A, const u16* __restrict__ Bt,
               OT* __restrict__ C, const float* __restrict__ rscale,
               const float* __restrict__ bias,
               int K, int lda, int ldb, int ldc) {
    __shared__ __align__(16) u16 Alds[BM * LSTR];
    __shared__ __align__(16) u16 Blds[BN * LSTR];
    const int t = threadIdx.x;
    const int m0 = blockIdx.x * BM, n0 = blockIdx.y * BN;
    const int wave = t >> 6, lane = t & 63, quad = lane >> 4, lo = lane & 15;
    const int wm = (wave >> 1) * 64, wn = (wave & 1) * 32;

    f32x4 acc[4][2];
#pragma unroll
    for (int a = 0; a < 4; a++)
#pragma unroll
        for (int b = 0; b < 2; b++) acc[a][b] = (f32x4){0.f, 0.f, 0.f, 0.f};

    for (int k0 = 0; k0 < K; k0 += BK) {
        __syncthreads();
        if (ALAYOUT == 0) {
            // A row-major: thread t loads A[m0 + t/2][k0 + (t&1)*16 .. +15]
            const int r = t >> 1, c0 = (t & 1) * 16;
            const float4* src = (const float4*)(A + (size_t)(m0 + r) * lda + k0 + c0);
            float4 f[4];
#pragma unroll
            for (int i = 0; i < 4; i++) f[i] = src[i];
            u16 tmp[16];
#pragma unroll
            for (int i = 0; i < 4; i++) {
                tmp[4 * i + 0] = f2b(f[i].x); tmp[4 * i + 1] = f2b(f[i].y);
                tmp[4 * i + 2] = f2b(f[i].z); tmp[4 * i + 3] = f2b(f[i].w);
            }
            *(uint4*)&Alds[r * LSTR + c0]     = *(uint4*)&tmp[0];
            *(uint4*)&Alds[r * LSTR + c0 + 8] = *(uint4*)&tmp[8];
        } else {
            // A = H^T: memory is contiguous in m for fixed k -> transpose in LDS.
            // thread t: k-pair kp=t>>4, m = (t&15) + i*16; paired b32 writes,
            // lanes 0..15 have consecutive m -> bank stride 20 -> 2-way alias (free).
            const int kp = t >> 4;
            const int mg = t & 15;
            const float* a0 = A + (size_t)(k0 + 2 * kp) * lda + m0;
            const float* a1 = a0 + lda;
#pragma unroll
            for (int i = 0; i < 8; i++) {
                int m = mg + i * 16;
                u32 pk = (u32)f2b(a0[m]) | ((u32)f2b(a1[m]) << 16);
                *(u32*)&Alds[m * LSTR + 2 * kp] = pk;
            }
        }
        {   // B tile: Bt rows n0..n0+63, 32 bf16 each -> fragment-ready layout
            const int n = t >> 2, c0 = (t & 3) * 8;
            const uint4* src = (const uint4*)(Bt + (size_t)(n0 + n) * ldb + k0 + c0);
            *(uint4*)&Blds[n * LSTR + c0] = *src;
        }
        __syncthreads();

        bf16x8 af[4], bfr[2];
#pragma unroll
        for (int mt = 0; mt < 4; mt++)
            af[mt] = *(const bf16x8*)&Alds[(wm + mt * 16 + lo) * LSTR + quad * 8];
#pragma unroll
        for (int nt = 0; nt < 2; nt++)
            bfr[nt] = *(const bf16x8*)&Blds[(wn + nt * 16 + lo) * LSTR + quad * 8];
#pragma unroll
        for (int mt = 0; mt < 4; mt++)
#pragma unroll
            for (int nt = 0; nt < 2; nt++)
                acc[mt][nt] = __builtin_amdgcn_mfma_f32_16x16x32_bf16(af[mt], bfr[nt], acc[mt][nt], 0, 0, 0);
    }

    // epilogue: D[row=quad*4+i][col=lo] per 16x16 tile (m89/m91-verified layout)
#pragma unroll
    for (int mt = 0; mt < 4; mt++) {
        int rbase = m0 + wm + mt * 16 + quad * 4;
#pragma unroll
        for (int i = 0; i < 4; i++) {
            float rs = rscale ? rscale[rbase + i] : 1.f;
#pragma unroll
            for (int nt = 0; nt < 2; nt++) {
                int cidx = n0 + wn + nt * 16 + lo;
                float v = acc[mt][nt][i] * rs;
                if (BIAS) v += bias[cidx];
                stf(&C[(size_t)(rbase + i) * ldc + cidx], v);
            }
        }
    }
}

// ---------------- launch ----------------

extern "C" void kernel_launch(void* const* d_in, const int* in_sizes, int n_in,
                              void* d_out, int out_size, void* d_ws, size_t ws_size,
                              hipStream_t stream) {
    const float* x    = (const float*)d_in[0];
    const float* H    = (const float*)d_in[1];
    const float* W    = (const float*)d_in[2];
    const float* V    = (const float*)d_in[3];
    const float* bias = (const float*)d_in[4];
    float* out  = (float*)d_out;                       // (N, FT)
    float* wout = out + (size_t)N_NODES * FT;          // (E,)

    float* wsf   = (float*)d_ws;
    float* xv    = wsf;               // 8192 f
    float* zsum  = wsf + 8192;        // 4096 f
    float* desum = wsf + 12288;       // 4096 f
    float* wde   = wsf + 16384;       // 4096 f
    float* degv  = wsf + 20480;       // 8192 f   -> ends at byte 114688
    char* wsb = (char*)d_ws;
    u16* WT    = (u16*)(wsb + 114688);                 // (FT,FT) bf16, W^T        -> ends 638976
    u16* doutb = (u16*)(wsb + 638976);                 // (N,FT) bf16 8MB          -> ends 9027584
    u16* t2    = (u16*)(wsb + 638976);                 // (E,FT) bf16 4MB, reuses dout region
    u16* t2T   = (u16*)(wsb + 638976 + 4194304);       // (FT,E) bf16 4MB
    u16* doutT = (u16*)(wsb + 9027584);                // (FT,N) bf16 8MB          -> ends 17416192
    (void)in_sizes; (void)n_in; (void)out_size; (void)ws_size;

    // fp32 scalar path: xv -> (z, deg_e) -> w, wde -> deg_v
    zero_kernel<<<32, 256, 0, stream>>>(zsum, 8192);   // zsum+desum contiguous
    xv_kernel<<<N_NODES / 4, 256, 0, stream>>>(x, V, xv);
    colsum_kernel<<<dim3(N_EDGES / 256, N_NODES / 128), 256, 0, stream>>>(H, xv, zsum, desum);
    sigmoid_kernel<<<N_EDGES / 256, 256, 0, stream>>>(zsum, desum, wout, wde);
    degv_kernel<<<N_NODES / 4, 256, 0, stream>>>(H, wout, degv);

    // G1: dout = degv ⊙ (x @ W)   [bf16 out]
    transpose_kernel<float, u16><<<dim3(FT / 32, FT / 32), dim3(32, 8), 0, stream>>>(W, WT, FT, FT);
    gemm_bf16<0, u16, false><<<dim3(N_NODES / BM, FT / BN), 256, 0, stream>>>(
        x, WT, doutb, degv, nullptr, FT, FT, FT, FT);

    // G2: t2 = wde ⊙ (H^T @ dout)   [A = H^T via in-LDS transpose staging]
    transpose_kernel<u16, u16><<<dim3(FT / 32, N_NODES / 32), dim3(32, 8), 0, stream>>>(doutb, doutT, N_NODES, FT);
    gemm_bf16<1, u16, false><<<dim3(N_EDGES / BM, FT / BN), 256, 0, stream>>>(
        H, doutT, t2, wde, nullptr, N_NODES, N_EDGES, N_NODES, FT);

    // G3: out = degv ⊙ (H @ t2) + bias   [fp32 out]
    transpose_kernel<u16, u16><<<dim3(FT / 32, N_EDGES / 32), dim3(32, 8), 0, stream>>>(t2, t2T, N_EDGES, FT);
    gemm_bf16<0, float, true><<<dim3(N_NODES / BM, FT / BN), 256, 0, stream>>>(
        H, t2T, out, degv, bias, N_EDGES, N_EDGES, N_EDGES, FT);
}

// Round 2
// 489.619 us; speedup vs baseline: 1.1648x; 1.1648x over previous
//
#include <hip/hip_runtime.h>

// HGNN conv: out = degv ⊙ (H @ ((w*deg_e) ⊙ (H^T @ (degv ⊙ (x@W))))) + bias ; w = sigmoid(H^T (x V))
// N=8192, E=4096, F=512. Round 2: split-K GEMMs (occupancy fix), H stored as u8 (0/1),
// scale+convert fused into transposes.

#define N_NODES 8192
#define N_EDGES 4096
#define FT 512

typedef short bf16x8 __attribute__((ext_vector_type(8)));
typedef float f32x4 __attribute__((ext_vector_type(4)));
typedef unsigned short u16;
typedef unsigned int u32;
typedef unsigned char u8;

__device__ __forceinline__ u16 f2b(float f) {
    union { float f; u32 u; } v; v.f = f;
    u32 r = v.u + 0x7FFFu + ((v.u >> 16) & 1u);   // RNE
    return (u16)(r >> 16);
}

// ---------------- small kernels ----------------

__global__ __launch_bounds__(256) void zero_kernel(float* p, int n) {
    int i = blockIdx.x * 256 + threadIdx.x;
    if (i < n) p[i] = 0.f;
}

// xv[n] = x[n,:] . V   (one wave per row)
__global__ __launch_bounds__(256) void xv_kernel(const float* __restrict__ x,
                                                 const float* __restrict__ V,
                                                 float* __restrict__ xv) {
    int row = blockIdx.x * 4 + (threadIdx.x >> 6);
    int lane = threadIdx.x & 63;
    const float4* xr = (const float4*)(x + (size_t)row * FT);
    const float4* vr = (const float4*)V;
    float acc = 0.f;
#pragma unroll
    for (int i = 0; i < 2; i++) {
        int idx = i * 64 + lane;
        float4 a = xr[idx], b = vr[idx];
        acc += a.x * b.x + a.y * b.y + a.z * b.z + a.w * b.w;
    }
#pragma unroll
    for (int off = 32; off; off >>= 1) acc += __shfl_down(acc, off);
    if (lane == 0) xv[row] = acc;
}

// Fused: Hu8 = (u8)H ; zsum[e] += sum_n H[n,e]*xv[n] ; desum[e] += sum_n H[n,e]
__global__ __launch_bounds__(256) void cvt_colsum_kernel(const float* __restrict__ H,
                                                         const float* __restrict__ xv,
                                                         u8* __restrict__ Hu8,
                                                         float* __restrict__ zsum,
                                                         float* __restrict__ desum) {
    int e0 = (blockIdx.x * 256 + threadIdx.x) * 4;
    int n0 = blockIdx.y * 64;
    float z0 = 0.f, z1 = 0.f, z2 = 0.f, z3 = 0.f;
    float d0 = 0.f, d1 = 0.f, d2 = 0.f, d3 = 0.f;
#pragma unroll 4
    for (int i = 0; i < 64; i++) {
        int n = n0 + i;
        float4 h = *(const float4*)(H + (size_t)n * N_EDGES + e0);
        float xvn = xv[n];
        z0 += h.x * xvn; z1 += h.y * xvn; z2 += h.z * xvn; z3 += h.w * xvn;
        d0 += h.x; d1 += h.y; d2 += h.z; d3 += h.w;
        u32 p = (u32)h.x | ((u32)h.y << 8) | ((u32)h.z << 16) | ((u32)h.w << 24);
        *(u32*)(Hu8 + (size_t)n * N_EDGES + e0) = p;
    }
    atomicAdd(zsum + e0 + 0, z0); atomicAdd(zsum + e0 + 1, z1);
    atomicAdd(zsum + e0 + 2, z2); atomicAdd(zsum + e0 + 3, z3);
    atomicAdd(desum + e0 + 0, d0); atomicAdd(desum + e0 + 1, d1);
    atomicAdd(desum + e0 + 2, d2); atomicAdd(desum + e0 + 3, d3);
}

// w[e] = sigmoid(z[e]); wde[e] = w[e]*deg_e[e]
__global__ __launch_bounds__(256) void sigmoid_kernel(const float* __restrict__ zsum,
                                                      const float* __restrict__ desum,
                                                      float* __restrict__ w_out,
                                                      float* __restrict__ wde) {
    int e = blockIdx.x * 256 + threadIdx.x;
    float z = zsum[e];
    float wv = 1.f / (1.f + expf(-z));
    w_out[e] = wv;
    wde[e] = wv * desum[e];
}

// degv[n] = Hu8[n,:] . w   (one wave per row)
__global__ __launch_bounds__(256) void degv_kernel(const u8* __restrict__ Hu8,
                                                   const float* __restrict__ w,
                                                   float* __restrict__ degv) {
    int row = blockIdx.x * 4 + (threadIdx.x >> 6);
    int lane = threadIdx.x & 63;
    const u32* hr = (const u32*)(Hu8 + (size_t)row * N_EDGES);
    const float4* wr = (const float4*)w;
    float acc = 0.f;
#pragma unroll
    for (int i = 0; i < 16; i++) {
        int idx = i * 64 + lane;
        u32 h4 = hr[idx];
        float4 ww = wr[idx];
        if (h4 & 0x000000FFu) acc += ww.x;
        if (h4 & 0x0000FF00u) acc += ww.y;
        if (h4 & 0x00FF0000u) acc += ww.z;
        if (h4 & 0xFF000000u) acc += ww.w;
    }
#pragma unroll
    for (int off = 32; off; off >>= 1) acc += __shfl_down(acc, off);
    if (lane == 0) degv[row] = acc;
}

// W (FT,FT) fp32 -> WT (FT,FT) bf16 transposed
__global__ void wt_kernel(const float* __restrict__ src, u16* __restrict__ dst) {
    __shared__ float tile[32][33];
    int tx = threadIdx.x, ty = threadIdx.y;
    int c = blockIdx.x * 32 + tx;
    int r0 = blockIdx.y * 32;
#pragma unroll
    for (int i = 0; i < 4; i++)
        tile[ty + i * 8][tx] = src[(size_t)(r0 + ty + i * 8) * FT + c];
    __syncthreads();
#pragma unroll
    for (int i = 0; i < 4; i++)
        dst[(size_t)(blockIdx.x * 32 + ty + i * 8) * FT + r0 + tx] = f2b(tile[tx][ty + i * 8]);
}

// dst[c,r] = f2b(scale[r] * src[r,c]); src (R,C) fp32, dst (C,R) bf16
__global__ void scaleT_kernel(const float* __restrict__ src, u16* __restrict__ dst,
                              const float* __restrict__ scale, int R, int C) {
    __shared__ float tile[32][33];
    int tx = threadIdx.x, ty = threadIdx.y;
    int c = blockIdx.x * 32 + tx;
    int r0 = blockIdx.y * 32;
#pragma unroll
    for (int i = 0; i < 4; i++) {
        int r = r0 + ty + i * 8;
        tile[ty + i * 8][tx] = scale[r] * src[(size_t)r * C + c];
    }
    __syncthreads();
#pragma unroll
    for (int i = 0; i < 4; i++)
        dst[(size_t)(blockIdx.x * 32 + ty + i * 8) * R + r0 + tx] = f2b(tile[tx][ty + i * 8]);
}

// out[n,f] = degv[n]*src[f,n] + bias[f]; src (FT,N) fp32, out (N,FT) fp32
__global__ void finalT_kernel(const float* __restrict__ src, float* __restrict__ out,
                              const float* __restrict__ degv, const float* __restrict__ bias) {
    __shared__ float tile[32][33];
    int tx = threadIdx.x, ty = threadIdx.y;
    int n = blockIdx.x * 32 + tx;
    int f0 = blockIdx.y * 32;
#pragma unroll
    for (int i = 0; i < 4; i++)
        tile[ty + i * 8][tx] = src[(size_t)(f0 + ty + i * 8) * N_NODES + n];
    __syncthreads();
    int nw = blockIdx.x * 32;
#pragma unroll
    for (int i = 0; i < 4; i++) {
        int row = nw + ty + i * 8;
        out[(size_t)row * FT + f0 + tx] = degv[row] * tile[tx][ty + i * 8] + bias[f0 + tx];
    }
}

// ---------------- MFMA GEMM with split-K ----------------
// C[m,n] += sum_{k in chunk} A[m,k]*B[k,n]
// ASRC: 0 = fp32 row-major (convert to bf16), 1 = bf16 row-major (copy),
//       2 = u8 with A[m,k] = Au8[k*lda + m] (H^T case: in-LDS transpose + expand)
// BSRC: 0 = bf16 Bt[n*ldb+k] (copy), 1 = u8 Bt[n*ldb+k] (expand)
// EPI:  0 = plain fp32 store, 1 = atomicAdd fp32
// 128x64 tile, BK=32, 4 waves (2x2), each wave 64x32 via 4x2 of 16x16x32 MFMAs.

#define BM 128
#define BN 64
#define BK 32
#define LSTR 40   // LDS row stride in bf16 elts (BK+8 pad)

__device__ __forceinline__ u32 expand2(u32 b0, u32 b1) {
    // two 0/1 bytes -> packed 2x bf16 {b0, b1}
    return (b0 ? 0x00003F80u : 0u) | (b1 ? 0x3F800000u : 0u);
}

template <int ASRC, int BSRC, int EPI>
__global__ __launch_bounds__(256)
void gemm2(const void* __restrict__ Ap, const void* __restrict__ Bp,
           float* __restrict__ C, int KC, int lda, int ldb, int ldc) {
    __shared__ __align__(16) u16 Alds[BM * LSTR];
    __shared__ __align__(16) u16 Blds[BN * LSTR];
    const int t = threadIdx.x;
    const int m0 = blockIdx.x * BM, n0 = blockIdx.y * BN;
    const int kbase = blockIdx.z * KC;
    const int wave = t >> 6, lane = t & 63, quad = lane >> 4, lo = lane & 15;
    const int wm = (wave >> 1) * 64, wn = (wave & 1) * 32;

    f32x4 acc[4][2];
#pragma unroll
    for (int a = 0; a < 4; a++)
#pragma unroll
        for (int b = 0; b < 2; b++) acc[a][b] = (f32x4){0.f, 0.f, 0.f, 0.f};

    for (int kk = 0; kk < KC; kk += BK) {
        const int k0 = kbase + kk;
        __syncthreads();
        if (ASRC == 0) {
            const float* A = (const float*)Ap;
            const int r = t >> 1, c0 = (t & 1) * 16;
            const float4* src = (const float4*)(A + (size_t)(m0 + r) * lda + k0 + c0);
            float4 f[4];
#pragma unroll
            for (int i = 0; i < 4; i++) f[i] = src[i];
            u16 tmp[16];
#pragma unroll
            for (int i = 0; i < 4; i++) {
                tmp[4 * i + 0] = f2b(f[i].x); tmp[4 * i + 1] = f2b(f[i].y);
                tmp[4 * i + 2] = f2b(f[i].z); tmp[4 * i + 3] = f2b(f[i].w);
            }
            *(uint4*)&Alds[r * LSTR + c0]     = *(uint4*)&tmp[0];
            *(uint4*)&Alds[r * LSTR + c0 + 8] = *(uint4*)&tmp[8];
        } else if (ASRC == 1) {
            const u16* A = (const u16*)Ap;
            const int r = t >> 1, c0 = (t & 1) * 16;
            const uint4* src = (const uint4*)(A + (size_t)(m0 + r) * lda + k0 + c0);
            *(uint4*)&Alds[r * LSTR + c0]     = src[0];
            *(uint4*)&Alds[r * LSTR + c0 + 8] = src[1];
        } else {
            // A[m,k] = Au8[k*lda + m]: in-LDS transpose + u8->bf16 expand.
            // thread t: k-pair kp, m-pair base me; loads u16 (2 m's) from 2 k-rows.
            const u8* A = (const u8*)Ap;
            const int kp = t >> 4;          // 0..15 -> k = 2kp, 2kp+1
            const int me = (t & 15) * 2;    // m even base
            const u8* a0 = A + (size_t)(k0 + 2 * kp) * lda + m0;
            const u8* a1 = a0 + lda;
#pragma unroll
            for (int i = 0; i < 4; i++) {
                int m = me + 32 * i;
                u32 w0 = *(const u16*)(a0 + m);   // bytes: H[k][m], H[k][m+1]
                u32 w1 = *(const u16*)(a1 + m);   // bytes: H[k+1][m], H[k+1][m+1]
                *(u32*)&Alds[(m + 0) * LSTR + 2 * kp] = expand2(w0 & 0xFFu, w1 & 0xFFu);
                *(u32*)&Alds[(m + 1) * LSTR + 2 * kp] = expand2(w0 & 0xFF00u, w1 & 0xFF00u);
            }
        }
        if (BSRC == 0) {
            const u16* B = (const u16*)Bp;
            const int n = t >> 2, c0 = (t & 3) * 8;
            *(uint4*)&Blds[n * LSTR + c0] =
                *(const uint4*)(B + (size_t)(n0 + n) * ldb + k0 + c0);
        } else {
            const u8* B = (const u8*)Bp;
            const int n = t >> 2, c0 = (t & 3) * 8;
            uint2 v = *(const uint2*)(B + (size_t)(n0 + n) * ldb + k0 + c0);
            u32 o[4];
            o[0] = expand2(v.x & 0xFFu, v.x & 0xFF00u);
            o[1] = expand2(v.x & 0xFF0000u, v.x & 0xFF000000u);
            o[2] = expand2(v.y & 0xFFu, v.y & 0xFF00u);
            o[3] = expand2(v.y & 0xFF0000u, v.y & 0xFF000000u);
            *(uint4*)&Blds[n * LSTR + c0] = *(uint4*)o;
        }
        __syncthreads();

        bf16x8 af[4], bfr[2];
#pragma unroll
        for (int mt = 0; mt < 4; mt++)
            af[mt] = *(const bf16x8*)&Alds[(wm + mt * 16 + lo) * LSTR + quad * 8];
#pragma unroll
        for (int nt = 0; nt < 2; nt++)
            bfr[nt] = *(const bf16x8*)&Blds[(wn + nt * 16 + lo) * LSTR + quad * 8];
#pragma unroll
        for (int mt = 0; mt < 4; mt++)
#pragma unroll
            for (int nt = 0; nt < 2; nt++)
                acc[mt][nt] = __builtin_amdgcn_mfma_f32_16x16x32_bf16(af[mt], bfr[nt], acc[mt][nt], 0, 0, 0);
    }

    // epilogue: D[row=quad*4+i][col=lo] per 16x16 tile
#pragma unroll
    for (int mt = 0; mt < 4; mt++) {
        int rbase = m0 + wm + mt * 16 + quad * 4;
#pragma unroll
        for (int i = 0; i < 4; i++) {
#pragma unroll
            for (int nt = 0; nt < 2; nt++) {
                int cidx = n0 + wn + nt * 16 + lo;
                float v = acc[mt][nt][i];
                if (EPI == 0) C[(size_t)(rbase + i) * ldc + cidx] = v;
                else          atomicAdd(&C[(size_t)(rbase + i) * ldc + cidx], v);
            }
        }
    }
}

// ---------------- launch ----------------

extern "C" void kernel_launch(void* const* d_in, const int* in_sizes, int n_in,
                              void* d_out, int out_size, void* d_ws, size_t ws_size,
                              hipStream_t stream) {
    const float* x    = (const float*)d_in[0];
    const float* H    = (const float*)d_in[1];
    const float* W    = (const float*)d_in[2];
    const float* V    = (const float*)d_in[3];
    const float* bias = (const float*)d_in[4];
    float* out  = (float*)d_out;                       // (N, FT)
    float* wout = out + (size_t)N_NODES * FT;          // (E,)
    (void)in_sizes; (void)n_in; (void)out_size; (void)ws_size;

    char* wsb = (char*)d_ws;
    float* wsf   = (float*)d_ws;
    float* xv    = wsf;               // 8192 f
    float* zsum  = wsf + 8192;        // 4096 f
    float* desum = wsf + 12288;       // 4096 f
    float* wde   = wsf + 16384;       // 4096 f
    float* degv  = wsf + 20480;       // 8192 f -> ends 114688 B
    u8*    Hu8   = (u8*)(wsb + 114688);                // 32 MB          -> 33669120
    u16*   WT    = (u16*)(wsb + 33669120);             // 512 KB bf16    -> 34193408
    float* dacc  = (float*)(wsb + 34193408);           // 16 MB fp32 (N,FT); reused as oaccT (FT,N)
    float* oaccT = dacc;
    float* t2acc = (float*)(wsb + 50970624);           // 8 MB fp32 (E,FT)
    u16*   doutT = (u16*)(wsb + 59359232);             // 8 MB bf16 (FT,N)
    u16*   t2T   = (u16*)(wsb + 67747840);             // 4 MB bf16 (FT,E) -> ends 71942144 (~68.6 MB)

    // fp32 scalar path
    zero_kernel<<<32, 256, 0, stream>>>(zsum, 8192);   // zsum+desum contiguous
    xv_kernel<<<N_NODES / 4, 256, 0, stream>>>(x, V, xv);
    cvt_colsum_kernel<<<dim3(4, 128), 256, 0, stream>>>(H, xv, Hu8, zsum, desum);
    sigmoid_kernel<<<N_EDGES / 256, 256, 0, stream>>>(zsum, desum, wout, wde);
    degv_kernel<<<N_NODES / 4, 256, 0, stream>>>(Hu8, wout, degv);
    wt_kernel<<<dim3(16, 16), dim3(32, 8), 0, stream>>>(W, WT);

    // zero dacc + t2acc (adjacent, 6M floats)
    zero_kernel<<<24576, 256, 0, stream>>>(dacc, 6291456);

    // G1: dacc = x @ W    (M=N_NODES, N=FT, K=512, split 2)
    gemm2<0, 0, 1><<<dim3(N_NODES / BM, FT / BN, 2), 256, 0, stream>>>(
        x, WT, dacc, 256, FT, FT, FT);
    // doutT[f,n] = degv[n] * dacc[n,f]  (bf16)
    scaleT_kernel<<<dim3(FT / 32, N_NODES / 32), dim3(32, 8), 0, stream>>>(
        dacc, doutT, degv, N_NODES, FT);

    // G2: t2acc = H^T @ dout   (M=E, N=FT, K=N_NODES, split 8)
    gemm2<2, 0, 1><<<dim3(N_EDGES / BM, FT / BN, 8), 256, 0, stream>>>(
        Hu8, doutT, t2acc, 1024, N_EDGES, N_NODES, FT);
    // t2T[f,e] = wde[e] * t2acc[e,f]  (bf16)
    scaleT_kernel<<<dim3(FT / 32, N_EDGES / 32), dim3(32, 8), 0, stream>>>(
        t2acc, t2T, wde, N_EDGES, FT);

    // zero oaccT (4M floats, aliases dacc)
    zero_kernel<<<16384, 256, 0, stream>>>(oaccT, 4194304);

    // G3: oaccT = t2T @ H^T-as-Bt   (outT[f,n] = sum_e t2T[f,e]*H[n,e]; M=FT, N=N_NODES, K=E, split 4)
    gemm2<1, 1, 1><<<dim3(FT / BM, N_NODES / BN, 4), 256, 0, stream>>>(
        t2T, Hu8, oaccT, 1024, N_EDGES, N_EDGES, N_NODES);

    // out[n,f] = degv[n]*oaccT[f,n] + bias[f]
    finalT_kernel<<<dim3(N_NODES / 32, FT / 32), dim3(32, 8), 0, stream>>>(
        oaccT, out, degv, bias);
}

// Round 3
// 432.549 us; speedup vs baseline: 1.3185x; 1.1319x over previous
//
#include <hip/hip_runtime.h>

// HGNN conv: out = degv ⊙ (H @ ((w*deg_e) ⊙ (H^T @ (degv ⊙ (x@W))))) + bias ; w = sigmoid(H^T (x V))
// N=8192, E=4096, F=512. R3: m97-style 128x128 GEMM (global_load_lds + 4x4 frags),
// H materialized both ways as u8 (row + col major) so all GEMM staging is k-contiguous.

#define N_NODES 8192
#define N_EDGES 4096
#define FT 512

typedef short bf16x8 __attribute__((ext_vector_type(8)));
typedef float f32x4 __attribute__((ext_vector_type(4)));
typedef unsigned short u16;
typedef unsigned int u32;
typedef unsigned char u8;

__device__ __forceinline__ u16 f2b(float f) {
    union { float f; u32 u; } v; v.f = f;
    u32 r = v.u + 0x7FFFu + ((v.u >> 16) & 1u);   // RNE
    return (u16)(r >> 16);
}
__device__ __forceinline__ u32 expand2(u32 b0, u32 b1) {
    // two 0/1 byte-flags -> packed 2x bf16 {b0, b1}
    return (b0 ? 0x00003F80u : 0u) | (b1 ? 0x3F800000u : 0u);
}

// ---------------- scalar-path kernels ----------------

__global__ __launch_bounds__(256) void zero_kernel(float* p, int n) {
    int i = blockIdx.x * 256 + threadIdx.x;
    if (i < n) p[i] = 0.f;
}

// xv[n] = x[n,:] . V
__global__ __launch_bounds__(256) void xv_kernel(const float* __restrict__ x,
                                                 const float* __restrict__ V,
                                                 float* __restrict__ xv) {
    int row = blockIdx.x * 4 + (threadIdx.x >> 6);
    int lane = threadIdx.x & 63;
    const float4* xr = (const float4*)(x + (size_t)row * FT);
    const float4* vr = (const float4*)V;
    float acc = 0.f;
#pragma unroll
    for (int i = 0; i < 2; i++) {
        int idx = i * 64 + lane;
        float4 a = xr[idx], b = vr[idx];
        acc += a.x * b.x + a.y * b.y + a.z * b.z + a.w * b.w;
    }
#pragma unroll
    for (int off = 32; off; off >>= 1) acc += __shfl_down(acc, off);
    if (lane == 0) xv[row] = acc;
}

// Hu8 = (u8)H ; zsum[e] += sum_n H[n,e]*xv[n] ; desum[e] += sum_n H[n,e]
__global__ __launch_bounds__(256) void cvt_colsum_kernel(const float* __restrict__ H,
                                                         const float* __restrict__ xv,
                                                         u8* __restrict__ Hu8,
                                                         float* __restrict__ zsum,
                                                         float* __restrict__ desum) {
    int e0 = (blockIdx.x * 256 + threadIdx.x) * 4;
    int n0 = blockIdx.y * 64;
    float z0 = 0.f, z1 = 0.f, z2 = 0.f, z3 = 0.f;
    float d0 = 0.f, d1 = 0.f, d2 = 0.f, d3 = 0.f;
#pragma unroll 4
    for (int i = 0; i < 64; i++) {
        int n = n0 + i;
        float4 h = *(const float4*)(H + (size_t)n * N_EDGES + e0);
        float xvn = xv[n];
        z0 += h.x * xvn; z1 += h.y * xvn; z2 += h.z * xvn; z3 += h.w * xvn;
        d0 += h.x; d1 += h.y; d2 += h.z; d3 += h.w;
        u32 p = (u32)h.x | ((u32)h.y << 8) | ((u32)h.z << 16) | ((u32)h.w << 24);
        *(u32*)(Hu8 + (size_t)n * N_EDGES + e0) = p;
    }
    atomicAdd(zsum + e0 + 0, z0); atomicAdd(zsum + e0 + 1, z1);
    atomicAdd(zsum + e0 + 2, z2); atomicAdd(zsum + e0 + 3, z3);
    atomicAdd(desum + e0 + 0, d0); atomicAdd(desum + e0 + 1, d1);
    atomicAdd(desum + e0 + 2, d2); atomicAdd(desum + e0 + 3, d3);
}

__global__ __launch_bounds__(256) void sigmoid_kernel(const float* __restrict__ zsum,
                                                      const float* __restrict__ desum,
                                                      float* __restrict__ w_out,
                                                      float* __restrict__ wde) {
    int e = blockIdx.x * 256 + threadIdx.x;
    float z = zsum[e];
    float wv = 1.f / (1.f + expf(-z));
    w_out[e] = wv;
    wde[e] = wv * desum[e];
}

// degv[n] = Hu8[n,:] . w
__global__ __launch_bounds__(256) void degv_kernel(const u8* __restrict__ Hu8,
                                                   const float* __restrict__ w,
                                                   float* __restrict__ degv) {
    int row = blockIdx.x * 4 + (threadIdx.x >> 6);
    int lane = threadIdx.x & 63;
    const u32* hr = (const u32*)(Hu8 + (size_t)row * N_EDGES);
    const float4* wr = (const float4*)w;
    float acc = 0.f;
#pragma unroll
    for (int i = 0; i < 16; i++) {
        int idx = i * 64 + lane;
        u32 h4 = hr[idx];
        float4 ww = wr[idx];
        if (h4 & 0x000000FFu) acc += ww.x;
        if (h4 & 0x0000FF00u) acc += ww.y;
        if (h4 & 0x00FF0000u) acc += ww.z;
        if (h4 & 0xFF000000u) acc += ww.w;
    }
#pragma unroll
    for (int off = 32; off; off >>= 1) acc += __shfl_down(acc, off);
    if (lane == 0) degv[row] = acc;
}

// W (FT,FT) fp32 -> WT (FT,FT) bf16 transposed
__global__ void wt_kernel(const float* __restrict__ src, u16* __restrict__ dst) {
    __shared__ float tile[32][33];
    int tx = threadIdx.x, ty = threadIdx.y;
    int c = blockIdx.x * 32 + tx;
    int r0 = blockIdx.y * 32;
#pragma unroll
    for (int i = 0; i < 4; i++)
        tile[ty + i * 8][tx] = src[(size_t)(r0 + ty + i * 8) * FT + c];
    __syncthreads();
#pragma unroll
    for (int i = 0; i < 4; i++)
        dst[(size_t)(blockIdx.x * 32 + ty + i * 8) * FT + r0 + tx] = f2b(tile[tx][ty + i * 8]);
}

// Hu8 (N,E) -> HTu8 (E,N) : 64x64 u8 tiles via LDS u32 + byte shuffles
__global__ __launch_bounds__(256) void transH_kernel(const u8* __restrict__ Hu8,
                                                     u8* __restrict__ HTu8) {
    __shared__ u32 tile[64][17];
    const int t = threadIdx.x;
    const int e0 = blockIdx.x * 64, n0 = blockIdx.y * 64;
    {
        int nl = t >> 2, seg = t & 3;
        uint4 v = *(const uint4*)(Hu8 + (size_t)(n0 + nl) * N_EDGES + e0 + seg * 16);
        tile[nl][seg * 4 + 0] = v.x; tile[nl][seg * 4 + 1] = v.y;
        tile[nl][seg * 4 + 2] = v.z; tile[nl][seg * 4 + 3] = v.w;
    }
    __syncthreads();
    int ew = t >> 4, ng = t & 15;           // e-word 0..15, n-group 0..15
    u32 a0 = tile[ng * 4 + 0][ew], a1 = tile[ng * 4 + 1][ew];
    u32 a2 = tile[ng * 4 + 2][ew], a3 = tile[ng * 4 + 3][ew];
#pragma unroll
    for (int i = 0; i < 4; i++) {
        u32 o = ((a0 >> (8 * i)) & 0xFFu) | (((a1 >> (8 * i)) & 0xFFu) << 8) |
                (((a2 >> (8 * i)) & 0xFFu) << 16) | (((a3 >> (8 * i)) & 0xFFu) << 24);
        *(u32*)(HTu8 + (size_t)(e0 + ew * 4 + i) * N_NODES + n0 + ng * 4) = o;
    }
}

// t2T[f,e] = f2b(wde[e] * sum_s Pt2[s][e][f])
__global__ void t2t_kernel(const float* __restrict__ P, const float* __restrict__ wde,
                           u16* __restrict__ t2T) {
    __shared__ float tile[32][33];
    int tx = threadIdx.x, ty = threadIdx.y;
    int f0 = blockIdx.x * 32, e0 = blockIdx.y * 32;
#pragma unroll
    for (int i = 0; i < 4; i++) {
        int e = e0 + ty + i * 8;
        size_t idx = (size_t)e * FT + f0 + tx;
        float s = P[idx] + P[idx + (size_t)N_EDGES * FT] +
                  P[idx + 2 * (size_t)N_EDGES * FT] + P[idx + 3 * (size_t)N_EDGES * FT];
        tile[ty + i * 8][tx] = wde[e] * s;
    }
    __syncthreads();
#pragma unroll
    for (int i = 0; i < 4; i++)
        t2T[(size_t)(f0 + ty + i * 8) * N_EDGES + e0 + tx] = f2b(tile[tx][ty + i * 8]);
}

// out[n,f] = degv[n]*(P0+P1)[n,f] + bias[f]
__global__ __launch_bounds__(256) void final_kernel(const float* __restrict__ P,
                                                    const float* __restrict__ degv,
                                                    const float* __restrict__ bias,
                                                    float* __restrict__ out) {
    int i4 = blockIdx.x * 256 + threadIdx.x;
    int base = i4 * 4;
    int n = base >> 9, f = base & 511;
    float4 a = *(const float4*)(P + base);
    float4 b = *(const float4*)(P + (size_t)N_NODES * FT + base);
    float4 bi = *(const float4*)(bias + f);
    float dv = degv[n];
    float4 o;
    o.x = dv * (a.x + b.x) + bi.x; o.y = dv * (a.y + b.y) + bi.y;
    o.z = dv * (a.z + b.z) + bi.z; o.w = dv * (a.w + b.w) + bi.w;
    *(float4*)(out + base) = o;
}

// ---------------- MFMA GEMM (m97 structure) ----------------
// 128x128 tile, BK=32, 4 waves (2x2), each wave 64x64 via 4x4 of 16x16x32 MFMAs.
// LDS unpadded [row][32] bf16 (global_load_lds-compatible; frag b128 reads are 2-way = free).
// ASRC: 0 = bf16 row-major via global_load_lds, 1 = u8 row-major (VALU expand)
// BSRC: 0 = bf16 Bt row-major via global_load_lds, 2 = fp32 Bt row-major (convert)
// EPI:  0 = fp32 partial store to Cp + z*Msz*512 (ldc=512), 1 = bf16 doutT store ldc=N_NODES, scale degv[col]

#define TBM 128
#define TBN 128
#define TBK 32

template <int ASRC, int BSRC, int EPI>
__global__ __launch_bounds__(256)
void gemm3(const void* __restrict__ Ap, const void* __restrict__ Bp,
           void* __restrict__ Cp, const float* __restrict__ degv,
           int KC, int lda, int ldb, int Msz) {
    __shared__ __align__(16) u16 Alds[TBM * TBK];
    __shared__ __align__(16) u16 Blds[TBN * TBK];
    const int t = threadIdx.x;
    const int m0 = blockIdx.x * TBM, n0 = blockIdx.y * TBN;
    const int kbase = blockIdx.z * KC;
    const int wave = t >> 6, lane = t & 63, quad = lane >> 4, lo = lane & 15;
    const int wm = (wave >> 1) * 64, wn = (wave & 1) * 64;

    f32x4 acc[4][4];
#pragma unroll
    for (int a = 0; a < 4; a++)
#pragma unroll
        for (int b = 0; b < 4; b++) acc[a][b] = (f32x4){0.f, 0.f, 0.f, 0.f};

    for (int kk = 0; kk < KC; kk += TBK) {
        const int k0 = kbase + kk;
        __syncthreads();
        // ---- stage A ----
        if (ASRC == 0) {
            const u16* A = (const u16*)Ap;
#pragma unroll
            for (int i = 0; i < 2; i++) {
                int c = t + i * 256;
                const u16* g = A + (size_t)(m0 + (c >> 2)) * lda + k0 + (c & 3) * 8;
                __builtin_amdgcn_global_load_lds((const u32*)g, (u32*)(Alds + c * 8), 16, 0, 0);
            }
        } else {
            const u8* A = (const u8*)Ap;
            const int r = t >> 1, h = (t & 1) * 16;
            uint4 v = *(const uint4*)(A + (size_t)(m0 + r) * lda + k0 + h);
            u32 o[8];
            o[0] = expand2(v.x & 0xFFu, v.x & 0xFF00u);
            o[1] = expand2(v.x & 0xFF0000u, v.x & 0xFF000000u);
            o[2] = expand2(v.y & 0xFFu, v.y & 0xFF00u);
            o[3] = expand2(v.y & 0xFF0000u, v.y & 0xFF000000u);
            o[4] = expand2(v.z & 0xFFu, v.z & 0xFF00u);
            o[5] = expand2(v.z & 0xFF0000u, v.z & 0xFF000000u);
            o[6] = expand2(v.w & 0xFFu, v.w & 0xFF00u);
            o[7] = expand2(v.w & 0xFF0000u, v.w & 0xFF000000u);
            *(uint4*)&Alds[r * TBK + h]     = *(uint4*)&o[0];
            *(uint4*)&Alds[r * TBK + h + 8] = *(uint4*)&o[4];
        }
        // ---- stage B ----
        if (BSRC == 0) {
            const u16* B = (const u16*)Bp;
#pragma unroll
            for (int i = 0; i < 2; i++) {
                int c = t + i * 256;
                const u16* g = B + (size_t)(n0 + (c >> 2)) * ldb + k0 + (c & 3) * 8;
                __builtin_amdgcn_global_load_lds((const u32*)g, (u32*)(Blds + c * 8), 16, 0, 0);
            }
        } else {
            const float* B = (const float*)Bp;
#pragma unroll
            for (int i = 0; i < 2; i++) {
                int c = t + i * 256;
                const float* g = B + (size_t)(n0 + (c >> 2)) * ldb + k0 + (c & 3) * 8;
                float4 f0 = *(const float4*)g;
                float4 f1 = *(const float4*)(g + 4);
                u16 tmp[8] = {f2b(f0.x), f2b(f0.y), f2b(f0.z), f2b(f0.w),
                              f2b(f1.x), f2b(f1.y), f2b(f1.z), f2b(f1.w)};
                *(uint4*)&Blds[c * 8] = *(uint4*)&tmp[0];
            }
        }
        __syncthreads();

        bf16x8 af[4], bfr[4];
#pragma unroll
        for (int mt = 0; mt < 4; mt++)
            af[mt] = *(const bf16x8*)&Alds[(wm + mt * 16 + lo) * TBK + quad * 8];
#pragma unroll
        for (int nt = 0; nt < 4; nt++)
            bfr[nt] = *(const bf16x8*)&Blds[(wn + nt * 16 + lo) * TBK + quad * 8];
#pragma unroll
        for (int mt = 0; mt < 4; mt++)
#pragma unroll
            for (int nt = 0; nt < 4; nt++)
                acc[mt][nt] = __builtin_amdgcn_mfma_f32_16x16x32_bf16(af[mt], bfr[nt], acc[mt][nt], 0, 0, 0);
    }

    // epilogue: D[row=quad*4+i][col=lo] per 16x16 tile
    if (EPI == 0) {
        float* C = (float*)Cp + (size_t)blockIdx.z * Msz * 512;
#pragma unroll
        for (int mt = 0; mt < 4; mt++) {
            int rb = m0 + wm + mt * 16 + quad * 4;
#pragma unroll
            for (int i = 0; i < 4; i++)
#pragma unroll
                for (int nt = 0; nt < 4; nt++)
                    C[(size_t)(rb + i) * 512 + n0 + wn + nt * 16 + lo] = acc[mt][nt][i];
        }
    } else {
        u16* C = (u16*)Cp;
        float dv[4];
#pragma unroll
        for (int nt = 0; nt < 4; nt++) dv[nt] = degv[n0 + wn + nt * 16 + lo];
#pragma unroll
        for (int mt = 0; mt < 4; mt++) {
            int rb = m0 + wm + mt * 16 + quad * 4;
#pragma unroll
            for (int i = 0; i < 4; i++)
#pragma unroll
                for (int nt = 0; nt < 4; nt++)
                    C[(size_t)(rb + i) * N_NODES + n0 + wn + nt * 16 + lo] =
                        f2b(acc[mt][nt][i] * dv[nt]);
        }
    }
}

// ---------------- launch ----------------

extern "C" void kernel_launch(void* const* d_in, const int* in_sizes, int n_in,
                              void* d_out, int out_size, void* d_ws, size_t ws_size,
                              hipStream_t stream) {
    const float* x    = (const float*)d_in[0];
    const float* H    = (const float*)d_in[1];
    const float* W    = (const float*)d_in[2];
    const float* V    = (const float*)d_in[3];
    const float* bias = (const float*)d_in[4];
    float* out  = (float*)d_out;                       // (N, FT)
    float* wout = out + (size_t)N_NODES * FT;          // (E,)
    (void)in_sizes; (void)n_in; (void)out_size; (void)ws_size;

    char* wsb = (char*)d_ws;
    float* wsf   = (float*)d_ws;
    float* xv    = wsf;               // 8192 f
    float* zsum  = wsf + 8192;        // 4096 f
    float* desum = wsf + 12288;       // 4096 f
    float* wde   = wsf + 16384;       // 4096 f
    float* degv  = wsf + 20480;       // 8192 f -> 114688 B
    u8*    Hu8   = (u8*)(wsb + 114688);                  // 32 MB  -> 33,669,120
    u8*    HTu8  = (u8*)(wsb + 33669120);                // 32 MB  -> 67,223,552
    u16*   WT    = (u16*)(wsb + 67223552);               // 0.5 MB -> 67,747,840
    u16*   doutT = (u16*)(wsb + 67747840);               // 8 MB   -> 76,136,448
    u16*   t2T   = (u16*)(wsb + 76136448);               // 4 MB   -> 80,330,752
    float* P     = (float*)(wsb + 80330752);             // 32 MB partials (shared G2/G3) -> 113,885,184 (~109 MB)

    // scalar path
    zero_kernel<<<32, 256, 0, stream>>>(zsum, 8192);     // zsum+desum contiguous
    xv_kernel<<<N_NODES / 4, 256, 0, stream>>>(x, V, xv);
    cvt_colsum_kernel<<<dim3(4, 128), 256, 0, stream>>>(H, xv, Hu8, zsum, desum);
    sigmoid_kernel<<<N_EDGES / 256, 256, 0, stream>>>(zsum, desum, wout, wde);
    degv_kernel<<<N_NODES / 4, 256, 0, stream>>>(Hu8, wout, degv);
    wt_kernel<<<dim3(16, 16), dim3(32, 8), 0, stream>>>(W, WT);
    transH_kernel<<<dim3(N_EDGES / 64, N_NODES / 64), 256, 0, stream>>>(Hu8, HTu8);

    // G1': doutT[f,n] = degv[n] * sum_fi WT[f,fi]*x[n,fi]   (M=512, N=8192, K=512)
    gemm3<0, 2, 1><<<dim3(FT / TBM, N_NODES / TBN, 1), 256, 0, stream>>>(
        WT, x, doutT, degv, FT, FT, FT, 0);

    // G2: Pt2[z][e][f] = partial sum_n HTu8[e,n]*doutT[f,n]  (M=4096, N=512, K=8192, S=4)
    gemm3<1, 0, 0><<<dim3(N_EDGES / TBM, FT / TBN, 4), 256, 0, stream>>>(
        HTu8, doutT, P, nullptr, N_NODES / 4, N_NODES, N_NODES, N_EDGES);

    // t2T[f,e] = wde[e] * sum_s Pt2
    t2t_kernel<<<dim3(FT / 32, N_EDGES / 32), dim3(32, 8), 0, stream>>>(P, wde, t2T);

    // G3: Pout[z][n][f] = partial sum_e Hu8[n,e]*t2T[f,e]   (M=8192, N=512, K=4096, S=2)
    gemm3<1, 0, 0><<<dim3(N_NODES / TBM, FT / TBN, 2), 256, 0, stream>>>(
        Hu8, t2T, P, nullptr, N_EDGES / 2, N_EDGES, N_EDGES, N_NODES);

    // out = degv ⊙ (P0+P1) + bias
    final_kernel<<<(N_NODES * FT / 4) / 256, 256, 0, stream>>>(P, degv, bias, out);
}